// Round 1
// baseline (384.761 us; speedup 1.0000x reference)
//
#include <hip/hip_runtime.h>
#include <math.h>

// Fused ConvTranspose2d(64->64,k4,s2,p1) + MaxPool2x2 + Hardtanh + mean + tanh.
//
// Phase decomposition: conv output oh = 2*ih - 1 + kh  =>  kh = oh+1-2*ih.
// Pooled pixel (ph,pw) = max of conv outputs (2ph,2pw),(2ph,2pw+1),(2ph+1,2pw),(2ph+1,2pw+1):
//   y00 += xb_c*w[1][1] + xb_l*w[1][3] + xa_c*w[3][1] + xa_l*w[3][3]
//   y01 += xb_c*w[1][2] + xb_r*w[1][0] + xa_c*w[3][2] + xa_r*w[3][0]
//   y10 += xb_c*w[2][1] + xb_l*w[2][3] + xc_c*w[0][1] + xc_l*w[0][3]
//   y11 += xb_c*w[2][2] + xb_r*w[2][0] + xc_c*w[0][2] + xc_r*w[0][0]
// where xa = input row ph-1, xb = row ph, xc = row ph+1; _l/_c/_r = col pw-1/pw/pw+1.

#define CI_CHUNK 16
#define XS_STRIDE 76   // floats: slots 0..7 zero (cols -8..-1), 8..71 = cols 0..63, 72..75 zero

__global__ __launch_bounds__(256, 2) void convt_pool_mean_kernel(
    const float* __restrict__ x,     // [32][64][64][64]
    const float* __restrict__ w,     // [64 ci][64 co][4][4]
    const float* __restrict__ bias,  // [64]
    float* __restrict__ partial)     // [2048] pre-zeroed, atomicAdd target
{
    __shared__ float xs[CI_CHUNK][4][XS_STRIDE];
    __shared__ float wl[CI_CHUNK][16][16];

    const int rp = blockIdx.x;   // 0..31: pooled rows 2rp, 2rp+1
    const int g4 = blockIdx.y;   // 0..3 : co group of 16
    const int b  = blockIdx.z;   // 0..31

    const int tid    = threadIdx.x;
    const int co_idx = tid >> 4;      // 0..15
    const int grp    = tid & 15;      // 0..15
    const int r      = grp >> 3;      // 0..1  pooled row within the pair
    const int cg     = grp & 7;       // 0..7  col group
    const int c0     = cg * 8;        // first pooled col of this thread

    const int   co = g4 * 16 + co_idx;
    const float bv = bias[co];

    float y00[8], y01[8], y10[8], y11[8];
    #pragma unroll
    for (int p = 0; p < 8; ++p) { y00[p]=0.f; y01[p]=0.f; y10[p]=0.f; y11[p]=0.f; }

    // staging thread mapping: 64 (ci,row) pairs x 4 col-quarters
    const int  pair  = tid >> 2;      // 0..63
    const int  sci   = pair >> 2;     // 0..15
    const int  strow = pair & 3;      // 0..3  (tile row = input row 2rp-1+strow)
    const int  q     = tid & 3;       // 0..3
    const int  ih    = 2 * rp - 1 + strow;
    const bool rowok = (ih >= 0) && (ih < 64);

    for (int c = 0; c < 4; ++c) {
        const int ci0 = c * CI_CHUNK;

        // ---- stage x chunk: 16 ci x 4 rows x 64 cols ----
        {
            float4 v0, v1, v2, v3;
            if (rowok) {
                const float4* src = reinterpret_cast<const float4*>(
                    x + (((size_t)(b * 64 + ci0 + sci) * 64 + ih) * 64 + q * 16));
                v0 = src[0]; v1 = src[1]; v2 = src[2]; v3 = src[3];
            } else {
                v0 = v1 = v2 = v3 = make_float4(0.f, 0.f, 0.f, 0.f);
            }
            float4* dst = reinterpret_cast<float4*>(&xs[sci][strow][8 + q * 16]);
            dst[0] = v0; dst[1] = v1; dst[2] = v2; dst[3] = v3;
            const float4 z = make_float4(0.f, 0.f, 0.f, 0.f);
            if (q == 0) {
                float4* zp = reinterpret_cast<float4*>(&xs[sci][strow][0]);
                zp[0] = z; zp[1] = z;
            } else if (q == 3) {
                float4* zp = reinterpret_cast<float4*>(&xs[sci][strow][72]);
                zp[0] = z;
            }
        }
        // ---- stage w chunk: 16 ci x 16 co x 16 ----
        {
            const int wci = tid >> 4;
            const int wco = tid & 15;
            const float4* src = reinterpret_cast<const float4*>(
                w + ((size_t)(ci0 + wci) * 1024 + (size_t)(g4 * 16 + wco) * 16));
            float4* dst = reinterpret_cast<float4*>(&wl[wci][wco][0]);
            dst[0] = src[0]; dst[1] = src[1]; dst[2] = src[2]; dst[3] = src[3];
        }
        __syncthreads();

        #pragma unroll
        for (int ci = 0; ci < CI_CHUNK; ++ci) {
            float wv[16];
            {
                const float4* wp = reinterpret_cast<const float4*>(&wl[ci][co_idx][0]);
                float4 a = wp[0], bq = wp[1], cq = wp[2], d = wp[3];
                wv[0]=a.x;  wv[1]=a.y;  wv[2]=a.z;  wv[3]=a.w;
                wv[4]=bq.x; wv[5]=bq.y; wv[6]=bq.z; wv[7]=bq.w;
                wv[8]=cq.x; wv[9]=cq.y; wv[10]=cq.z;wv[11]=cq.w;
                wv[12]=d.x; wv[13]=d.y; wv[14]=d.z; wv[15]=d.w;
            }
            float xa[10], xb[10], xc[10];
            // arr[j] = x[ci][trow][c0-1+j]
            #define LOADROW(trow, arr)                                              \
            {                                                                       \
                const float* base = &xs[ci][(trow)][8 + c0];                        \
                const float4 m0 = *reinterpret_cast<const float4*>(base);           \
                const float4 m1 = *reinterpret_cast<const float4*>(base + 4);       \
                arr[0] = base[-1];                                                  \
                arr[1]=m0.x; arr[2]=m0.y; arr[3]=m0.z; arr[4]=m0.w;                 \
                arr[5]=m1.x; arr[6]=m1.y; arr[7]=m1.z; arr[8]=m1.w;                 \
                arr[9] = base[8];                                                   \
            }
            LOADROW(r,     xa)   // input row ph-1
            LOADROW(r + 1, xb)   // input row ph
            LOADROW(r + 2, xc)   // input row ph+1
            #undef LOADROW

            #pragma unroll
            for (int p = 0; p < 8; ++p) {
                const float bl = xb[p], bc = xb[p+1], br = xb[p+2];
                const float al = xa[p], ac = xa[p+1], ar = xa[p+2];
                const float cl = xc[p], cc = xc[p+1], cr = xc[p+2];
                y00[p] = fmaf(bc, wv[5],  fmaf(bl, wv[7],  fmaf(ac, wv[13], fmaf(al, wv[15], y00[p]))));
                y01[p] = fmaf(bc, wv[6],  fmaf(br, wv[4],  fmaf(ac, wv[14], fmaf(ar, wv[12], y01[p]))));
                y10[p] = fmaf(bc, wv[9],  fmaf(bl, wv[11], fmaf(cc, wv[1],  fmaf(cl, wv[3],  y10[p]))));
                y11[p] = fmaf(bc, wv[10], fmaf(br, wv[8],  fmaf(cc, wv[2],  fmaf(cr, wv[0],  y11[p]))));
            }
        }
        __syncthreads();
    }

    // epilogue: maxpool + bias + hardtanh + local sum
    float local = 0.f;
    #pragma unroll
    for (int p = 0; p < 8; ++p) {
        float m = fmaxf(fmaxf(y00[p], y01[p]), fmaxf(y10[p], y11[p])) + bv;
        m = fminf(fmaxf(m, -1.f), 1.f);
        local += m;
    }
    // reduce across the 16 pixel-group lanes sharing this co (contiguous 16-lane span)
    local += __shfl_xor(local, 8, 64);
    local += __shfl_xor(local, 4, 64);
    local += __shfl_xor(local, 2, 64);
    local += __shfl_xor(local, 1, 64);
    if (grp == 0) atomicAdd(&partial[b * 64 + co], local);
}

__global__ void finalize_kernel(const float* __restrict__ partial, float* __restrict__ out)
{
    const int i = blockIdx.x * blockDim.x + threadIdx.x;
    if (i < 2048) out[i] = tanhf(partial[i] * (1.0f / 4096.0f));
}

extern "C" void kernel_launch(void* const* d_in, const int* in_sizes, int n_in,
                              void* d_out, int out_size, void* d_ws, size_t ws_size,
                              hipStream_t stream)
{
    const float* x  = (const float*)d_in[0];
    const float* w  = (const float*)d_in[1];
    const float* b  = (const float*)d_in[2];
    float* out = (float*)d_out;
    float* ws  = (float*)d_ws;

    hipMemsetAsync(ws, 0, 2048 * sizeof(float), stream);

    dim3 grid(32, 4, 32);  // (row-pair, co-group, batch)
    convt_pool_mean_kernel<<<grid, 256, 0, stream>>>(x, w, b, ws);
    finalize_kernel<<<8, 256, 0, stream>>>(ws, out);
}

// Round 2
// 128.620 us; speedup vs baseline: 2.9915x; 2.9915x over previous
//
#include <hip/hip_runtime.h>
#include <math.h>

// Fused ConvTranspose2d(64->64,k4,s2,p1) + MaxPool2x2 + Hardtanh + mean + tanh
// via bf16 MFMA implicit GEMM.
//
// Quad decomposition (verified exact in round 1, absmax 0.0):
//   pooled(ph,pw) = max over quads q of  y_q = sum_{t=0..3} x[ph+dh][pw+dw] * w[ci][co][kh][kw]
//   (dh,dw,kh,kw) tables below.
// GEMM view per (q,t): C[px, co] += A[px, ci] * B[ci, co],  K = 64 ci.
// MFMA 16x16x32 bf16: A lane l: row=l&15, k=(l>>4)*8+j (8 contig bf16 = b128)
//                     B lane l: col=l&15, k=(l>>4)*8+j
//                     C lane l: col=l&15, row=(l>>4)*4+j   [guide m89, HW-verified]

typedef __attribute__((ext_vector_type(8))) short short8;
typedef __attribute__((ext_vector_type(4))) float f32x4;

#define XS_ROW 66
#define XS_CI 72          // halfwords per (row,iw) slot: 64 ci + 8 pad (kills phase-aliasing)
#define XS_CI_U32 36

__device__ __forceinline__ unsigned short f2bf(float f) {
    unsigned int u = __builtin_bit_cast(unsigned int, f);
    u += 0x7fffu + ((u >> 16) & 1u);   // round-to-nearest-even
    return (unsigned short)(u >> 16);
}

// ---------------------------------------------------------------------------
// Weight prep: repack w[ci][co][4][4] fp32 into ready-made bf16 B-fragments
// wsB layout: halfword index = (((qt*4 + n)*2 + kb2)*64 + lane)*8 + j
//   qt = q*4+t, n = co tile (16 co), kb2 = ci half (32), lane = MFMA lane, j = 0..7
//   element: ci = kb2*32 + (lane>>4)*8 + j, co = n*16 + (lane&15), w[ci][co][kh][kw]
// Also zeroes the 2048-float partial-sum buffer.
// ---------------------------------------------------------------------------
__global__ void wprep_kernel(const float* __restrict__ w,
                             unsigned short* __restrict__ wsB,
                             float* __restrict__ partial)
{
    const int g = blockIdx.x * 256 + threadIdx.x;   // 0..16383, one u64 chunk each
    const int jh  = g & 1;            // j 0..3 or 4..7
    const int l   = (g >> 1) & 63;
    const int kb2 = (g >> 7) & 1;
    const int n   = (g >> 8) & 3;
    const int qt  = g >> 10;          // 0..15
    const int q = qt >> 2, t = qt & 3;

    const int kh = (q < 2) ? ((t < 2) ? 1 : 3) : ((t < 2) ? 2 : 0);
    const int kw = ((q & 1) == 0) ? ((t & 1) ? 3 : 1) : ((t & 1) ? 0 : 2);

    const int co  = n * 16 + (l & 15);
    const int ci0 = kb2 * 32 + (l >> 4) * 8 + jh * 4;

    unsigned short r[4];
    #pragma unroll
    for (int j = 0; j < 4; ++j)
        r[j] = f2bf(w[((size_t)(ci0 + j) * 64 + co) * 16 + kh * 4 + kw]);

    unsigned long long pk = (unsigned long long)r[0]
                          | ((unsigned long long)r[1] << 16)
                          | ((unsigned long long)r[2] << 32)
                          | ((unsigned long long)r[3] << 48);
    *(unsigned long long*)(wsB + (size_t)g * 4) = pk;

    if (g < 2048) partial[g] = 0.f;
}

// ---------------------------------------------------------------------------
// Main kernel: block = (row-pair rp, batch b), 128 threads = 2 waves.
// Wave w computes pooled row ph0+w (64 px) x all 64 co, 4x4 MFMA tile grid.
// ---------------------------------------------------------------------------
__global__ __launch_bounds__(128, 2) void convt_mfma_kernel(
    const float* __restrict__ x,           // [32][64][64][64]
    const float* __restrict__ bias,        // [64]
    const unsigned short* __restrict__ wsB,
    float* __restrict__ partial)           // [2048]
{
    __shared__ unsigned int xs[4 * XS_ROW * XS_CI_U32];   // 38016 B

    const int rp  = blockIdx.x;    // 0..31
    const int b   = blockIdx.y;    // 0..31
    const int ph0 = rp * 2;
    const int tid = threadIdx.x;

    // ---- stage x tile: input rows ph0-1..ph0+2, iw -1..64, all 64 ci (bf16) ----
    {
        const int iw   = tid & 63;
        const int half = tid >> 6;
        #pragma unroll
        for (int r4 = 0; r4 < 4; ++r4) {
            const int  ih    = ph0 - 1 + r4;
            const bool rowok = ((unsigned)ih < 64u);
            #pragma unroll
            for (int it = 0; it < 16; ++it) {
                const int ci = it * 4 + half * 2;
                float v0 = 0.f, v1 = 0.f;
                if (rowok) {
                    const size_t base = (((size_t)(b * 64 + ci)) * 64 + ih) * 64 + iw;
                    v0 = x[base];
                    v1 = x[base + 4096];   // ci+1
                }
                const unsigned int pk = (unsigned)f2bf(v0) | ((unsigned)f2bf(v1) << 16);
                xs[(r4 * XS_ROW + iw + 1) * XS_CI_U32 + (ci >> 1)] = pk;
                if (iw == 0)  xs[(r4 * XS_ROW + 0 ) * XS_CI_U32 + (ci >> 1)] = 0u;
                if (iw == 63) xs[(r4 * XS_ROW + 65) * XS_CI_U32 + (ci >> 1)] = 0u;
            }
        }
    }
    __syncthreads();

    const int wv   = tid >> 6;      // wave 0/1 -> pooled row ph0+wv
    const int lane = tid & 63;
    const int p    = lane & 15;
    const int hi   = lane >> 4;

    const unsigned short* xs16 = (const unsigned short*)xs;
    // A-frag base (dh=0,dw=0,m=0,kb2=0): row r4 = wv+1, iwi = p+1, +hi*8 ci
    const int abase = ((wv + 1) * XS_ROW + (p + 1)) * XS_CI + hi * 8;
    const unsigned short* wB = wsB + (size_t)lane * 8;

    constexpr int DHt[16] = {0,0,-1,-1, 0,0,-1,-1, 0,0,1,1, 0,0,1,1};
    constexpr int DWt[16] = {0,-1,0,-1, 0,1,0,1, 0,-1,0,-1, 0,1,0,1};

    f32x4 vmax[4][4];
    f32x4 acc[4][4];

    #pragma unroll
    for (int q = 0; q < 4; ++q) {
        #pragma unroll
        for (int m = 0; m < 4; ++m)
            #pragma unroll
            for (int n = 0; n < 4; ++n)
                acc[m][n] = (f32x4){0.f, 0.f, 0.f, 0.f};

        #pragma unroll
        for (int t = 0; t < 4; ++t) {
            const int qt = q * 4 + t;
            const int dh = DHt[qt], dw = DWt[qt];
            #pragma unroll
            for (int kb2 = 0; kb2 < 2; ++kb2) {
                short8 Bf[4];
                #pragma unroll
                for (int n = 0; n < 4; ++n)
                    Bf[n] = *(const short8*)(wB + (((size_t)(qt * 4 + n) * 2 + kb2) << 9));

                short8 Af[4];
                const int ao = abase + dh * (XS_ROW * XS_CI) + dw * XS_CI + kb2 * 32;
                #pragma unroll
                for (int m = 0; m < 4; ++m)
                    Af[m] = *(const short8*)(xs16 + ao + m * (16 * XS_CI));

                #pragma unroll
                for (int m = 0; m < 4; ++m)
                    #pragma unroll
                    for (int n = 0; n < 4; ++n)
                        acc[m][n] = __builtin_amdgcn_mfma_f32_16x16x32_bf16(
                            Af[m], Bf[n], acc[m][n], 0, 0, 0);
            }
        }

        if (q == 0) {
            #pragma unroll
            for (int m = 0; m < 4; ++m)
                #pragma unroll
                for (int n = 0; n < 4; ++n)
                    vmax[m][n] = acc[m][n];
        } else {
            #pragma unroll
            for (int m = 0; m < 4; ++m)
                #pragma unroll
                for (int n = 0; n < 4; ++n)
                    #pragma unroll
                    for (int j = 0; j < 4; ++j)
                        vmax[m][n][j] = fmaxf(vmax[m][n][j], acc[m][n][j]);
        }
    }

    // ---- epilogue: bias + hardtanh + sum over this wave's 64 px ----
    #pragma unroll
    for (int n = 0; n < 4; ++n) {
        const float bv = bias[n * 16 + p];
        float s = 0.f;
        #pragma unroll
        for (int m = 0; m < 4; ++m)
            #pragma unroll
            for (int j = 0; j < 4; ++j) {
                float v = vmax[m][n][j] + bv;
                v = fminf(fmaxf(v, -1.f), 1.f);
                s += v;
            }
        s += __shfl_xor(s, 16, 64);
        s += __shfl_xor(s, 32, 64);
        if (hi == 0) atomicAdd(&partial[b * 64 + n * 16 + p], s);
    }
}

__global__ void finalize_kernel(const float* __restrict__ partial, float* __restrict__ out)
{
    const int i = blockIdx.x * blockDim.x + threadIdx.x;
    if (i < 2048) out[i] = tanhf(partial[i] * (1.0f / 4096.0f));
}

extern "C" void kernel_launch(void* const* d_in, const int* in_sizes, int n_in,
                              void* d_out, int out_size, void* d_ws, size_t ws_size,
                              hipStream_t stream)
{
    (void)in_sizes; (void)n_in; (void)out_size; (void)ws_size;
    const float* x  = (const float*)d_in[0];
    const float* w  = (const float*)d_in[1];
    const float* bi = (const float*)d_in[2];
    float* out = (float*)d_out;

    unsigned short* wsB = (unsigned short*)d_ws;                   // 262144 B
    float* partial = (float*)((char*)d_ws + 262144);               // 8192 B

    wprep_kernel<<<64, 256, 0, stream>>>(w, wsB, partial);
    dim3 grid(32, 32);
    convt_mfma_kernel<<<grid, 128, 0, stream>>>(x, bi, wsB, partial);
    finalize_kernel<<<8, 256, 0, stream>>>(partial, out);
}